// Round 8
// baseline (157.363 us; speedup 1.0000x reference)
//
#include <hip/hip_runtime.h>
#include <cstdint>
#include <cstddef>

// ---------------------------------------------------------------------------
// SelfAttention (b=4, C=64, 128x128) — MFMA bf16, round 8.
// Math as rounds 2-7 (no-max softmax, Schraudolph fast-exp2, pi-permuted
// Vpp/Wop feeding MFMA B-operands by bitcast, hi/lo bf16 conv in k_qkv).
// Round-8: software-pipelined S: iter i computes S(i+1) (operands loaded two
// iters ahead) while exp-VALU consumes S(i) from the previous iter — no
// consumer within MFMA latency of its producer. k_attn at (256,3) to hold
// the two S register banks without spill. k_lsum: barrier-free 64-thr
// blocks, k split 16-ways (16 waves/CU), same pipeline. k_qkv: pos-half
// split (grid 512, 32 KB LDS).
// ---------------------------------------------------------------------------

#define LOG2E 1.44269504088896340736f
#define FE_A 8388608.0f        // 2^23
#define FE_B 1064993098.0f     // 127*2^23 - 360118 (fast exp2 bias)

typedef __attribute__((ext_vector_type(8)))  __bf16 bf8_t;
typedef __attribute__((ext_vector_type(16))) float  fx16;

__device__ __forceinline__ unsigned short f2bf(float f) {
  unsigned int u = __builtin_bit_cast(unsigned int, f);
  u += 0x7FFFu + ((u >> 16) & 1u);   // round-nearest-even
  return (unsigned short)(u >> 16);
}
__device__ __forceinline__ float bf2f(unsigned short h) {
  unsigned int u = ((unsigned int)h) << 16;
  return __builtin_bit_cast(float, u);
}
__device__ __forceinline__ unsigned int pk2(unsigned short lo, unsigned short hi) {
  return (unsigned int)lo | ((unsigned int)hi << 16);
}
// involution permutation on a 16-group: swap middle two quads
__device__ __forceinline__ int pi16(int s) {
  int m = (s >> 2) & 3;
  return (m == 1 || m == 2) ? (s ^ 12) : s;
}
__device__ __forceinline__ unsigned fe_u(float s) {
  return (unsigned)fmaf(s, FE_A, FE_B);
}
__device__ __forceinline__ float fe_f(float s) {
  return __builtin_bit_cast(float, fe_u(s));
}
__device__ __forceinline__ unsigned fe_pk(float s0, float s1) {
  return __builtin_amdgcn_perm(fe_u(s1), fe_u(s0), 0x07060302);
}

#define MFMA __builtin_amdgcn_mfma_f32_32x32x16_bf16

// ----------------------- K1: fused q/k/v via MFMA ---------------------------
// Blocks 0..511 = (b, rowpair T, pos-half ph). Stage x[64c][2r x 64col] as
// bf16 hi/lo planes into 32 KB LDS (chunk-swizzled rows). 4 waves =
// (Mt = wv>>1, cg = wv&1); each computes D[32ch x 32col] for r=0/1 with
// 3-MFMA hi/lo products. Epilogue: q stores (Mt0), 2x2 pool = reg-max +
// shfl_xor(1), KpB (*LOG2E folded) + Vp. Block 512 packs Wo.
__global__ void __launch_bounds__(256) k_qkv(const float* __restrict__ x,
                                             const float* __restrict__ Wq,
                                             const float* __restrict__ Wk,
                                             const float* __restrict__ Wv,
                                             const float* __restrict__ Wo,
                                             unsigned short* __restrict__ Qp,
                                             unsigned short* __restrict__ KpB,
                                             float* __restrict__ Vp,
                                             unsigned short* __restrict__ Wop) {
  if (blockIdx.x == 512) {                         // Wo -> bf16, pi on c-cols
    for (int i = threadIdx.x; i < 2048; i += 256) {
      int c = i & 31;
      Wop[i] = f2bf(Wo[(i & ~31) | (c & 16) | pi16(c & 15)]);
    }
    return;
  }
  __shared__ unsigned int xs[128 * 64];            // 32 KB: [pos][16 chunks][4 dw]
  int t = threadIdx.x;
  int b = blockIdx.x >> 7, rr = blockIdx.x & 127;
  int T = rr >> 1, ph = rr & 1;
  {
    int pos = t & 127, cslot = t >> 7;             // pos = r*64 + c
    int r = pos >> 6, c = pos & 63;
    const float* xb =
        x + (size_t)b * (64 * 16384) + T * 256 + r * 128 + ph * 64 + c;
    int sw = pos & 15;
    unsigned int* row = xs + pos * 64;
#pragma unroll
    for (int i = 0; i < 16; ++i) {
      int p = cslot * 16 + i;
      float g0 = xb[(size_t)(2 * p) * 16384];
      float g1 = xb[(size_t)(2 * p + 1) * 16384];
      unsigned short h0 = f2bf(g0), h1 = f2bf(g1);
      unsigned short l0 = f2bf(g0 - bf2f(h0)), l1 = f2bf(g1 - bf2f(h1));
      int q = p >> 2, d = p & 3;
      row[((q + sw) & 15) * 4 + d] = pk2(h0, h1);
      row[((q + 8 + sw) & 15) * 4 + d] = pk2(l0, l1);
    }
  }
  // per-wave A-fragments (weights hi/lo)
  int wv = t >> 6, lane = t & 63;
  int cg = wv & 1, Mt = wv >> 1;
  int m = lane & 31, h = lane >> 5;
  const float* wrow;
  float scale = 1.0f;
  bool zero = false;
  if (Mt == 0) {
    if (m < 8) wrow = Wq + m * 64;
    else if (m < 16) { wrow = Wk + (m - 8) * 64; scale = LOG2E; }
    else wrow = Wv + (m - 16) * 64;
  } else {
    if (m < 16) wrow = Wv + (m + 16) * 64;
    else { wrow = Wq; zero = true; }
  }
  bf8_t Ahi[4], Alo[4];
#pragma unroll
  for (int kk = 0; kk < 4; ++kk) {
    unsigned short hi8[8], lo8[8];
#pragma unroll
    for (int j = 0; j < 8; ++j) {
      float w = zero ? 0.f : wrow[kk * 16 + h * 8 + j] * scale;
      unsigned short wh = f2bf(w);
      hi8[j] = wh;
      lo8[j] = f2bf(w - bf2f(wh));
    }
    uint4 uh, ul;
    uh.x = pk2(hi8[0], hi8[1]); uh.y = pk2(hi8[2], hi8[3]);
    uh.z = pk2(hi8[4], hi8[5]); uh.w = pk2(hi8[6], hi8[7]);
    ul.x = pk2(lo8[0], lo8[1]); ul.y = pk2(lo8[2], lo8[3]);
    ul.z = pk2(lo8[4], lo8[5]); ul.w = pk2(lo8[6], lo8[7]);
    Ahi[kk] = __builtin_bit_cast(bf8_t, uh);
    Alo[kk] = __builtin_bit_cast(bf8_t, ul);
  }
  __syncthreads();
  fx16 z;
#pragma unroll
  for (int i = 0; i < 16; ++i) z[i] = 0.f;
  fx16 D0 = z, D1 = z;
#pragma unroll
  for (int r = 0; r < 2; ++r) {
    fx16 acc = z;
    int pos = r * 64 + cg * 32 + (lane & 31);
    const unsigned int* row = xs + pos * 64;
    int sw = pos & 15;
#pragma unroll
    for (int kk = 0; kk < 4; ++kk) {
      int q = 2 * kk + h;
      bf8_t Bh = *reinterpret_cast<const bf8_t*>(&row[((q + sw) & 15) * 4]);
      bf8_t Bl = *reinterpret_cast<const bf8_t*>(&row[((q + 8 + sw) & 15) * 4]);
      acc = MFMA(Ahi[kk], Bh, acc, 0, 0, 0);
      acc = MFMA(Ahi[kk], Bl, acc, 0, 0, 0);
      acc = MFMA(Alo[kk], Bh, acc, 0, 0, 0);
    }
    if (r == 0) D0 = acc; else D1 = acc;
  }
  uint2 z2; z2.x = z2.y = 0u;
  if (Mt == 0) {                                   // q rows 0-7
#pragma unroll
    for (int r = 0; r < 2; ++r) {
      const fx16& D = r ? D1 : D0;
      int gpos = T * 256 + r * 128 + ph * 64 + cg * 32 + (lane & 31);
      unsigned short* qd = Qp + ((size_t)b * 16384 + gpos) * 16;
      uint2 qa;
      qa.x = pk2(f2bf(D[0]), f2bf(D[1]));
      qa.y = pk2(f2bf(D[2]), f2bf(D[3]));
      *reinterpret_cast<uint2*>(qd + h * 4) = qa;
      *reinterpret_cast<uint2*>(qd + 8 + h * 4) = z2;
    }
  }
  float pm[16];                                    // 2x2 maxpool
#pragma unroll
  for (int r0 = 0; r0 < 16; ++r0) {
    float a = fmaxf(D0[r0], __shfl_xor(D0[r0], 1));
    float bb = fmaxf(D1[r0], __shfl_xor(D1[r0], 1));
    pm[r0] = fmaxf(a, bb);
  }
  if ((lane & 1) == 0) {
    int cell = ph * 32 + cg * 16 + ((lane & 31) >> 1);
    size_t idx = (size_t)b * 4096 + T * 64 + cell;
    float* vd = Vp + idx * 32;
    if (Mt == 0) {
      uint2 kw;
      kw.x = pk2(f2bf(pm[4]), f2bf(pm[5]));
      kw.y = pk2(f2bf(pm[6]), f2bf(pm[7]));
      *reinterpret_cast<uint2*>(KpB + idx * 16 + h * 4) = kw;
      *reinterpret_cast<float4*>(vd + h * 4) = make_float4(pm[8], pm[9], pm[10], pm[11]);
      *reinterpret_cast<float4*>(vd + 8 + h * 4) = make_float4(pm[12], pm[13], pm[14], pm[15]);
    } else {
      *reinterpret_cast<uint2*>(KpB + idx * 16 + 8 + h * 4) = z2;
      *reinterpret_cast<float4*>(vd + 16 + h * 4) = make_float4(pm[0], pm[1], pm[2], pm[3]);
      *reinterpret_cast<float4*>(vd + 24 + h * 4) = make_float4(pm[4], pm[5], pm[6], pm[7]);
    }
  }
}

// --------------------- K2: partial l = sum exp2(S2) -------------------------
// grid 4096 = (b4 x fgpair64 x ks16), 64-thr blocks (one wave), barrier-free.
// FB=2 (64 f-rows), 32 chunks of 32 k. Pipelined: iter i computes S(i+1)
// while the exp-accumulate consumes S(i); Q prefetch 2-deep.
__global__ void __launch_bounds__(64, 4) k_lsum(const unsigned short* __restrict__ Qp,
                                                const unsigned short* __restrict__ KpB,
                                                float* __restrict__ Lpart) {
  int b = blockIdx.x >> 10, gp = (blockIdx.x >> 4) & 63, ks = blockIdx.x & 15;
  int lane = threadIdx.x & 63;
  int half = lane >> 5, l31 = lane & 31;
  const unsigned short* kb =
      KpB + ((size_t)(b * 4096 + gp * 64 + l31)) * 16 + half * 8;
  bf8_t A0 = *reinterpret_cast<const bf8_t*>(kb);
  bf8_t A1 = *reinterpret_cast<const bf8_t*>(kb + 32 * 16);
  const unsigned short* qbase = Qp + ((size_t)b * 16384) * 16 + half * 8;
  fx16 z;
#pragma unroll
  for (int i = 0; i < 16; ++i) z[i] = 0.f;
  float l[32];
#pragma unroll
  for (int i = 0; i < 32; ++i) l[i] = 0.f;
  int t0 = ks * 32;
#define QLD(j) (*reinterpret_cast<const bf8_t*>( \
    qbase + (size_t)(((t0 + ((j) & 31)) * 32 + l31)) * 16))
  bf8_t Bc = QLD(0);
  fx16 sp0 = MFMA(A0, Bc, z, 0, 0, 0);
  fx16 sp1 = MFMA(A1, Bc, z, 0, 0, 0);
  Bc = QLD(1);
  bf8_t Bn = QLD(2);
  for (int i = 0; i < 32; ++i) {
    fx16 sn0 = MFMA(A0, Bc, z, 0, 0, 0);           // S(i+1)
    fx16 sn1 = MFMA(A1, Bc, z, 0, 0, 0);
#pragma unroll
    for (int r0 = 0; r0 < 16; ++r0) l[r0] += fe_f(sp0[r0]);
#pragma unroll
    for (int r0 = 0; r0 < 16; ++r0) l[16 + r0] += fe_f(sp1[r0]);
    sp0 = sn0; sp1 = sn1;
    Bc = Bn;
    Bn = QLD(i + 3);
  }
#undef QLD
#pragma unroll
  for (int r0 = 0; r0 < 32; ++r0)
    for (int d = 1; d < 32; d <<= 1) l[r0] += __shfl_xor(l[r0], d);
  if (l31 == 0) {
    size_t base = (size_t)ks * 16384 + b * 4096 + gp * 64;
#pragma unroll
    for (int r0 = 0; r0 < 16; ++r0) {
      int row = (r0 & 3) + 8 * (r0 >> 2) + 4 * half;
      Lpart[base + row] = l[r0];
      Lpart[base + 32 + row] = l[16 + r0];
    }
  }
}

// ------------------------------ K3: pack -----------------------------------
// Vpp[b][c][f'] bf16 = Vp[b][pi(f)][c] / sum_{ks<16} Lpart[ks][pi(f)].
__global__ void __launch_bounds__(256) k_pack(const float* __restrict__ Vp,
                                              const float* __restrict__ Lpart,
                                              unsigned short* __restrict__ Vpp) {
  int b = blockIdx.x >> 4, f0 = (blockIdx.x & 15) * 256;
  __shared__ unsigned short Tt[32][264];           // +8 pad, rows 16B-aligned
  int t = threadIdx.x;
  size_t li = (size_t)b * 4096 + f0 + t;
  float L = 0.f;
#pragma unroll
  for (int p = 0; p < 16; ++p) L += Lpart[(size_t)p * 16384 + li];
  float rl = 1.0f / L;
  const float* vp = Vp + li * 32;
  int fl = (t & ~15) | pi16(t & 15);               // destination column
  for (int c = 0; c < 32; ++c) Tt[c][fl] = f2bf(vp[c] * rl);
  __syncthreads();
  for (int u = t; u < 1024; u += 256) {            // 32 rows x 32 uint4
    int row = u >> 5, e0 = (u & 31) * 8;
    uint4 val = *reinterpret_cast<const uint4*>(&Tt[row][e0]);
    *reinterpret_cast<uint4*>(Vpp + ((size_t)b * 32 + row) * 4096 + f0 + e0) = val;
  }
}

// ------------------------- K4: attention + project --------------------------
// 256 thr (4 waves) per 64-k pair, grid 1024, KB=2, f split 4-ways.
// Pipelined: iter fc computes S(fc+1) from Ak loaded 2 iters ahead; exp
// consumes S(fc) from the previous iter; Av 1-deep, Ak 2-deep prefetch.
// (256,3): ~170-VGPR budget holds both S banks without spill.
__global__ void __launch_bounds__(256, 3) k_attn(const unsigned short* __restrict__ Qp,
                                                 const unsigned short* __restrict__ KpB,
                                                 const unsigned short* __restrict__ Vpp,
                                                 const unsigned short* __restrict__ Wop,
                                                 const float* __restrict__ x,
                                                 const float* __restrict__ gamma,
                                                 float* __restrict__ out) {
  int b = blockIdx.x >> 8, kp = blockIdx.x & 255;
  int wv = threadIdx.x >> 6, lane = threadIdx.x & 63;
  int half = lane >> 5, l31 = lane & 31;
  int kbase = kp * 64;
  const unsigned short* qb = Qp + ((size_t)b * 16384 + kbase + l31) * 16 + half * 8;
  bf8_t Bq0 = *reinterpret_cast<const bf8_t*>(qb);
  bf8_t Bq1 = *reinterpret_cast<const bf8_t*>(qb + 32 * 16);
  fx16 z;
#pragma unroll
  for (int i = 0; i < 16; ++i) z[i] = 0.f;
  fx16 acc0 = z, acc1 = z;
  const unsigned short* kpB = KpB + ((size_t)b * 4096 + l31) * 16 + half * 8;
  const unsigned short* vpB = Vpp + ((size_t)(b * 32 + l31)) * 4096 + half * 8;
  int c0 = wv * 32;                                // wave's first f-chunk
#define KLD(j) (*reinterpret_cast<const bf8_t*>(kpB + (size_t)((c0 + ((j) & 31)) * 32) * 16))
#define VLD(j, o) (*reinterpret_cast<const bf8_t*>(vpB + (c0 + ((j) & 31)) * 32 + (o)))
  bf8_t Akc = KLD(0);
  bf8_t Av0c = VLD(0, 0), Av1c = VLD(0, 16);
  fx16 sp0 = MFMA(Akc, Bq0, z, 0, 0, 0);           // S(0)
  fx16 sp1 = MFMA(Akc, Bq1, z, 0, 0, 0);
  Akc = KLD(1);                                    // Ak for S(1)
  bf8_t Av0n = VLD(1, 0), Av1n = VLD(1, 16);
  bf8_t Akin = KLD(2);
  for (int fc = 0; fc < 32; ++fc) {
    // S(fc+1) first: operands were loaded >=1 full iteration ago
    fx16 sn0 = MFMA(Akc, Bq0, z, 0, 0, 0);
    uint4 u00, u01;
    u00.x = fe_pk(sp0[0], sp0[1]);   u00.y = fe_pk(sp0[2], sp0[3]);
    u00.z = fe_pk(sp0[4], sp0[5]);   u00.w = fe_pk(sp0[6], sp0[7]);
    u01.x = fe_pk(sp0[8], sp0[9]);   u01.y = fe_pk(sp0[10], sp0[11]);
    u01.z = fe_pk(sp0[12], sp0[13]); u01.w = fe_pk(sp0[14], sp0[15]);
    acc0 = MFMA(Av0c, __builtin_bit_cast(bf8_t, u00), acc0, 0, 0, 0);
    acc0 = MFMA(Av1c, __builtin_bit_cast(bf8_t, u01), acc0, 0, 0, 0);
    fx16 sn1 = MFMA(Akc, Bq1, z, 0, 0, 0);
    uint4 u10, u11;
    u10.x = fe_pk(sp1[0], sp1[1]);   u10.y = fe_pk(sp1[2], sp1[3]);
    u10.z = fe_pk(sp1[4], sp1[5]);   u10.w = fe_pk(sp1[6], sp1[7]);
    u11.x = fe_pk(sp1[8], sp1[9]);   u11.y = fe_pk(sp1[10], sp1[11]);
    u11.z = fe_pk(sp1[12], sp1[13]); u11.w = fe_pk(sp1[14], sp1[15]);
    acc1 = MFMA(Av0c, __builtin_bit_cast(bf8_t, u10), acc1, 0, 0, 0);
    acc1 = MFMA(Av1c, __builtin_bit_cast(bf8_t, u11), acc1, 0, 0, 0);
    sp0 = sn0; sp1 = sn1;
    Akc = Akin; Av0c = Av0n; Av1c = Av1n;
    Akin = KLD(fc + 3);
    Av0n = VLD(fc + 2, 0); Av1n = VLD(fc + 2, 16);
  }
#undef KLD
#undef VLD
  __shared__ float sacc[4][2][4][64][4];           // 32 KB
#pragma unroll
  for (int j4 = 0; j4 < 4; ++j4) {
    *reinterpret_cast<float4*>(&sacc[wv][0][j4][lane][0]) =
        make_float4(acc0[4 * j4], acc0[4 * j4 + 1], acc0[4 * j4 + 2], acc0[4 * j4 + 3]);
    *reinterpret_cast<float4*>(&sacc[wv][1][j4][lane][0]) =
        make_float4(acc1[4 * j4], acc1[4 * j4 + 1], acc1[4 * j4 + 2], acc1[4 * j4 + 3]);
  }
  __syncthreads();
  if (wv >= 2) return;
  int kt = wv;
  int k = kbase + kt * 32 + l31;
  const float* xp = x + (size_t)b * 64 * 16384 + k;
  float xv0[16], xv1[16];                          // early residual prefetch
#pragma unroll
  for (int r0 = 0; r0 < 16; ++r0) {
    int row = (r0 & 3) + 8 * (r0 >> 2) + 4 * half;
    xv0[r0] = xp[(size_t)row * 16384];
    xv1[r0] = xp[(size_t)(row + 32) * 16384];
  }
  fx16 tot;
#pragma unroll
  for (int j4 = 0; j4 < 4; ++j4) {
    float4 a0 = *reinterpret_cast<const float4*>(&sacc[0][kt][j4][lane][0]);
    float4 a1 = *reinterpret_cast<const float4*>(&sacc[1][kt][j4][lane][0]);
    float4 a2 = *reinterpret_cast<const float4*>(&sacc[2][kt][j4][lane][0]);
    float4 a3 = *reinterpret_cast<const float4*>(&sacc[3][kt][j4][lane][0]);
    tot[4 * j4]     = (a0.x + a1.x) + (a2.x + a3.x);
    tot[4 * j4 + 1] = (a0.y + a1.y) + (a2.y + a3.y);
    tot[4 * j4 + 2] = (a0.z + a1.z) + (a2.z + a3.z);
    tot[4 * j4 + 3] = (a0.w + a1.w) + (a2.w + a3.w);
  }
  bf8_t Ob0, Ob1;
#pragma unroll
  for (int j = 0; j < 8; ++j) { Ob0[j] = (__bf16)tot[j]; Ob1[j] = (__bf16)tot[8 + j]; }
  const unsigned short* wb = Wop + l31 * 32 + half * 8;
  bf8_t Aw00 = *reinterpret_cast<const bf8_t*>(wb);
  bf8_t Aw01 = *reinterpret_cast<const bf8_t*>(wb + 16);
  bf8_t Aw10 = *reinterpret_cast<const bf8_t*>(wb + 1024);
  bf8_t Aw11 = *reinterpret_cast<const bf8_t*>(wb + 1024 + 16);
  fx16 y0 = MFMA(Aw00, Ob0, z, 0, 0, 0);
  y0 = MFMA(Aw01, Ob1, y0, 0, 0, 0);
  fx16 y1 = MFMA(Aw10, Ob0, z, 0, 0, 0);
  y1 = MFMA(Aw11, Ob1, y1, 0, 0, 0);
  float g = gamma[0];
  float* op = out + (size_t)b * 64 * 16384 + k;
#pragma unroll
  for (int r0 = 0; r0 < 16; ++r0) {
    int row = (r0 & 3) + 8 * (r0 >> 2) + 4 * half;
    op[(size_t)row * 16384]        = fmaf(g, y0[r0], xv0[r0]);
    op[(size_t)(row + 32) * 16384] = fmaf(g, y1[r0], xv1[r0]);
  }
}

// ---------------------------------------------------------------------------
extern "C" void kernel_launch(void* const* d_in, const int* in_sizes, int n_in,
                              void* d_out, int out_size, void* d_ws, size_t ws_size,
                              hipStream_t stream) {
  const float* x     = (const float*)d_in[0];
  const float* Wq    = (const float*)d_in[1];
  const float* Wk    = (const float*)d_in[2];
  const float* Wv    = (const float*)d_in[3];
  const float* Wo    = (const float*)d_in[4];
  const float* gamma = (const float*)d_in[5];
  float* out = (float*)d_out;
  char* ws = (char*)d_ws;
  // workspace layout (bytes)
  unsigned short* Qp    = (unsigned short*)(ws + 0);        // 2 MB
  unsigned short* KpB   = (unsigned short*)(ws + 2097152);  // 512 KB
  float*          Vp    = (float*)(ws + 2621440);           // 2 MB
  unsigned short* Vpp   = (unsigned short*)(ws + 4718592);  // 1 MB
  float*          Lpart = (float*)(ws + 5767168);           // 1 MB (16 planes)
  unsigned short* Wop   = (unsigned short*)(ws + 6815744);  // 4 KB

  k_qkv <<<dim3(513),  dim3(256), 0, stream>>>(x, Wq, Wk, Wv, Wo, Qp, KpB, Vp, Wop);
  k_lsum<<<dim3(4096), dim3(64),  0, stream>>>(Qp, KpB, Lpart);
  k_pack<<<dim3(64),   dim3(256), 0, stream>>>(Vp, Lpart, Vpp);
  k_attn<<<dim3(1024), dim3(256), 0, stream>>>(Qp, KpB, Vpp, Wop, x, gamma, out);
}

// Round 9
// 152.016 us; speedup vs baseline: 1.0352x; 1.0352x over previous
//
#include <hip/hip_runtime.h>
#include <cstdint>
#include <cstddef>

// ---------------------------------------------------------------------------
// SelfAttention (b=4, C=64, 128x128) — MFMA bf16, round 9.
// Math as rounds 2-8 (no-max softmax, Schraudolph fast-exp2, pi-permuted
// Vpp/Wop feeding MFMA B-operands by bitcast, hi/lo bf16 conv in k_qkv).
// Round-9: the compiler collapsed round-8's software pipeline (VGPR 68 vs
// ~140 needed) — exp was rescheduled next to its producing MFMA. Now the
// schedule is pinned with sched_group_barrier: x2-unrolled ping-pong banks
// (no copies), per half: produce-S MFMA(s) -> VMEM prefetch -> exp/pack VALU
// of the other bank -> PV MFMAs. k_lsum: 128-thr 2-wave barrier-free blocks
// (grid 4096, ~28 waves/CU), same pattern. k_pack: grid 256.
// ---------------------------------------------------------------------------

#define LOG2E 1.44269504088896340736f
#define FE_A 8388608.0f        // 2^23
#define FE_B 1064993098.0f     // 127*2^23 - 360118 (fast exp2 bias)

typedef __attribute__((ext_vector_type(8)))  __bf16 bf8_t;
typedef __attribute__((ext_vector_type(16))) float  fx16;

#if __has_builtin(__builtin_amdgcn_sched_group_barrier)
#define SGB(m, n) __builtin_amdgcn_sched_group_barrier(m, n, 0)
#else
#define SGB(m, n)
#endif
// masks: 0x2 VALU, 0x8 MFMA, 0x20 VMEM-read

__device__ __forceinline__ unsigned short f2bf(float f) {
  unsigned int u = __builtin_bit_cast(unsigned int, f);
  u += 0x7FFFu + ((u >> 16) & 1u);   // round-nearest-even
  return (unsigned short)(u >> 16);
}
__device__ __forceinline__ float bf2f(unsigned short h) {
  unsigned int u = ((unsigned int)h) << 16;
  return __builtin_bit_cast(float, u);
}
__device__ __forceinline__ unsigned int pk2(unsigned short lo, unsigned short hi) {
  return (unsigned int)lo | ((unsigned int)hi << 16);
}
// involution permutation on a 16-group: swap middle two quads
__device__ __forceinline__ int pi16(int s) {
  int m = (s >> 2) & 3;
  return (m == 1 || m == 2) ? (s ^ 12) : s;
}
__device__ __forceinline__ unsigned fe_u(float s) {
  return (unsigned)fmaf(s, FE_A, FE_B);   // v_fma + v_cvt_u32 (clamps neg -> 0)
}
__device__ __forceinline__ float fe_f(float s) {
  return __builtin_bit_cast(float, fe_u(s));
}
__device__ __forceinline__ unsigned fe_pk(float s0, float s1) {
  return __builtin_amdgcn_perm(fe_u(s1), fe_u(s0), 0x07060302);
}

#define MFMA __builtin_amdgcn_mfma_f32_32x32x16_bf16

// ----------------------- K1: fused q/k/v via MFMA ---------------------------
// Blocks 0..511 = (b, rowpair T, pos-half ph). Stage x[64c][2r x 64col] as
// bf16 hi/lo planes into 32 KB LDS (chunk-swizzled rows). 4 waves =
// (Mt = wv>>1, cg = wv&1); each computes D[32ch x 32col] for r=0/1 with
// 3-MFMA hi/lo products. Epilogue: q stores (Mt0), 2x2 pool = reg-max +
// shfl_xor(1), KpB (*LOG2E folded) + Vp. Block 512 packs Wo.
__global__ void __launch_bounds__(256) k_qkv(const float* __restrict__ x,
                                             const float* __restrict__ Wq,
                                             const float* __restrict__ Wk,
                                             const float* __restrict__ Wv,
                                             const float* __restrict__ Wo,
                                             unsigned short* __restrict__ Qp,
                                             unsigned short* __restrict__ KpB,
                                             float* __restrict__ Vp,
                                             unsigned short* __restrict__ Wop) {
  if (blockIdx.x == 512) {                         // Wo -> bf16, pi on c-cols
    for (int i = threadIdx.x; i < 2048; i += 256) {
      int c = i & 31;
      Wop[i] = f2bf(Wo[(i & ~31) | (c & 16) | pi16(c & 15)]);
    }
    return;
  }
  __shared__ unsigned int xs[128 * 64];            // 32 KB: [pos][16 chunks][4 dw]
  int t = threadIdx.x;
  int b = blockIdx.x >> 7, rr = blockIdx.x & 127;
  int T = rr >> 1, ph = rr & 1;
  {
    int pos = t & 127, cslot = t >> 7;             // pos = r*64 + c
    int r = pos >> 6, c = pos & 63;
    const float* xb =
        x + (size_t)b * (64 * 16384) + T * 256 + r * 128 + ph * 64 + c;
    int sw = pos & 15;
    unsigned int* row = xs + pos * 64;
#pragma unroll
    for (int i = 0; i < 16; ++i) {
      int p = cslot * 16 + i;
      float g0 = xb[(size_t)(2 * p) * 16384];
      float g1 = xb[(size_t)(2 * p + 1) * 16384];
      unsigned short h0 = f2bf(g0), h1 = f2bf(g1);
      unsigned short l0 = f2bf(g0 - bf2f(h0)), l1 = f2bf(g1 - bf2f(h1));
      int q = p >> 2, d = p & 3;
      row[((q + sw) & 15) * 4 + d] = pk2(h0, h1);
      row[((q + 8 + sw) & 15) * 4 + d] = pk2(l0, l1);
    }
  }
  // per-wave A-fragments (weights hi/lo)
  int wv = t >> 6, lane = t & 63;
  int cg = wv & 1, Mt = wv >> 1;
  int m = lane & 31, h = lane >> 5;
  const float* wrow;
  float scale = 1.0f;
  bool zero = false;
  if (Mt == 0) {
    if (m < 8) wrow = Wq + m * 64;
    else if (m < 16) { wrow = Wk + (m - 8) * 64; scale = LOG2E; }
    else wrow = Wv + (m - 16) * 64;
  } else {
    if (m < 16) wrow = Wv + (m + 16) * 64;
    else { wrow = Wq; zero = true; }
  }
  bf8_t Ahi[4], Alo[4];
#pragma unroll
  for (int kk = 0; kk < 4; ++kk) {
    unsigned short hi8[8], lo8[8];
#pragma unroll
    for (int j = 0; j < 8; ++j) {
      float w = zero ? 0.f : wrow[kk * 16 + h * 8 + j] * scale;
      unsigned short wh = f2bf(w);
      hi8[j] = wh;
      lo8[j] = f2bf(w - bf2f(wh));
    }
    uint4 uh, ul;
    uh.x = pk2(hi8[0], hi8[1]); uh.y = pk2(hi8[2], hi8[3]);
    uh.z = pk2(hi8[4], hi8[5]); uh.w = pk2(hi8[6], hi8[7]);
    ul.x = pk2(lo8[0], lo8[1]); ul.y = pk2(lo8[2], lo8[3]);
    ul.z = pk2(lo8[4], lo8[5]); ul.w = pk2(lo8[6], lo8[7]);
    Ahi[kk] = __builtin_bit_cast(bf8_t, uh);
    Alo[kk] = __builtin_bit_cast(bf8_t, ul);
  }
  __syncthreads();
  fx16 z;
#pragma unroll
  for (int i = 0; i < 16; ++i) z[i] = 0.f;
  fx16 D0 = z, D1 = z;
#pragma unroll
  for (int r = 0; r < 2; ++r) {
    fx16 acc = z;
    int pos = r * 64 + cg * 32 + (lane & 31);
    const unsigned int* row = xs + pos * 64;
    int sw = pos & 15;
#pragma unroll
    for (int kk = 0; kk < 4; ++kk) {
      int q = 2 * kk + h;
      bf8_t Bh = *reinterpret_cast<const bf8_t*>(&row[((q + sw) & 15) * 4]);
      bf8_t Bl = *reinterpret_cast<const bf8_t*>(&row[((q + 8 + sw) & 15) * 4]);
      acc = MFMA(Ahi[kk], Bh, acc, 0, 0, 0);
      acc = MFMA(Ahi[kk], Bl, acc, 0, 0, 0);
      acc = MFMA(Alo[kk], Bh, acc, 0, 0, 0);
    }
    if (r == 0) D0 = acc; else D1 = acc;
  }
  uint2 z2; z2.x = z2.y = 0u;
  if (Mt == 0) {                                   // q rows 0-7
#pragma unroll
    for (int r = 0; r < 2; ++r) {
      const fx16& D = r ? D1 : D0;
      int gpos = T * 256 + r * 128 + ph * 64 + cg * 32 + (lane & 31);
      unsigned short* qd = Qp + ((size_t)b * 16384 + gpos) * 16;
      uint2 qa;
      qa.x = pk2(f2bf(D[0]), f2bf(D[1]));
      qa.y = pk2(f2bf(D[2]), f2bf(D[3]));
      *reinterpret_cast<uint2*>(qd + h * 4) = qa;
      *reinterpret_cast<uint2*>(qd + 8 + h * 4) = z2;
    }
  }
  float pm[16];                                    // 2x2 maxpool
#pragma unroll
  for (int r0 = 0; r0 < 16; ++r0) {
    float a = fmaxf(D0[r0], __shfl_xor(D0[r0], 1));
    float bb = fmaxf(D1[r0], __shfl_xor(D1[r0], 1));
    pm[r0] = fmaxf(a, bb);
  }
  if ((lane & 1) == 0) {
    int cell = ph * 32 + cg * 16 + ((lane & 31) >> 1);
    size_t idx = (size_t)b * 4096 + T * 64 + cell;
    float* vd = Vp + idx * 32;
    if (Mt == 0) {
      uint2 kw;
      kw.x = pk2(f2bf(pm[4]), f2bf(pm[5]));
      kw.y = pk2(f2bf(pm[6]), f2bf(pm[7]));
      *reinterpret_cast<uint2*>(KpB + idx * 16 + h * 4) = kw;
      *reinterpret_cast<float4*>(vd + h * 4) = make_float4(pm[8], pm[9], pm[10], pm[11]);
      *reinterpret_cast<float4*>(vd + 8 + h * 4) = make_float4(pm[12], pm[13], pm[14], pm[15]);
    } else {
      *reinterpret_cast<uint2*>(KpB + idx * 16 + 8 + h * 4) = z2;
      *reinterpret_cast<float4*>(vd + 16 + h * 4) = make_float4(pm[0], pm[1], pm[2], pm[3]);
      *reinterpret_cast<float4*>(vd + 24 + h * 4) = make_float4(pm[4], pm[5], pm[6], pm[7]);
    }
  }
}

// --------------------- K2: partial l = sum exp2(S2) -------------------------
// grid 4096 = (b4 x fg128 x ks8), 128 thr (2 waves), barrier-free. Each wave
// owns k-slice (ks*2+wv) of 1024 k = 32 chunks, x2-unrolled ping-pong banks,
// schedule pinned: [1 MFMA][1 VMEM][48 VALU] per half.
__global__ void __launch_bounds__(128, 4) k_lsum(const unsigned short* __restrict__ Qp,
                                                 const unsigned short* __restrict__ KpB,
                                                 float* __restrict__ Lpart) {
  int b = blockIdx.x >> 10;
  int r = blockIdx.x & 1023;
  int fg = r >> 3, ks = r & 7;
  int wv = threadIdx.x >> 6, lane = threadIdx.x & 63;
  int half = lane >> 5, l31 = lane & 31;
  int slice = ks * 2 + wv;                         // 16 k-slices of 1024
  bf8_t A = *reinterpret_cast<const bf8_t*>(
      KpB + ((size_t)(b * 4096 + fg * 32 + l31)) * 16 + half * 8);
  const unsigned short* qbase = Qp + ((size_t)b * 16384) * 16 + half * 8;
  fx16 z;
#pragma unroll
  for (int i = 0; i < 16; ++i) z[i] = 0.f;
  float l[16];
#pragma unroll
  for (int i = 0; i < 16; ++i) l[i] = 0.f;
  int t0 = slice * 32;
#define QLD(j) (*reinterpret_cast<const bf8_t*>( \
    qbase + (size_t)(((t0 + ((j) & 31)) * 32 + l31)) * 16))
  bf8_t BqE = QLD(0);
  fx16 sE = MFMA(A, BqE, z, 0, 0, 0);              // S chunk 0
  bf8_t BqO = QLD(1);
  for (int it = 0; it < 16; ++it) {
    int e = 2 * it;
    // half 1: produce S(e+1); prefetch Q(e+2); consume S(e)
    fx16 sO = MFMA(A, BqO, z, 0, 0, 0);
    BqE = QLD(e + 2);
#pragma unroll
    for (int r0 = 0; r0 < 16; ++r0) l[r0] += fe_f(sE[r0]);
    SGB(0x8, 1); SGB(0x20, 1); SGB(0x2, 48);
    // half 2: produce S(e+2); prefetch Q(e+3); consume S(e+1)
    sE = MFMA(A, BqE, z, 0, 0, 0);
    BqO = QLD(e + 3);
#pragma unroll
    for (int r0 = 0; r0 < 16; ++r0) l[r0] += fe_f(sO[r0]);
    SGB(0x8, 1); SGB(0x20, 1); SGB(0x2, 48);
  }
#undef QLD
#pragma unroll
  for (int r0 = 0; r0 < 16; ++r0)
    for (int d = 1; d < 32; d <<= 1) l[r0] += __shfl_xor(l[r0], d);
  if (l31 == 0) {
    size_t base = (size_t)slice * 16384 + b * 4096 + fg * 32;
#pragma unroll
    for (int r0 = 0; r0 < 16; ++r0) {
      int row = (r0 & 3) + 8 * (r0 >> 2) + 4 * half;
      Lpart[base + row] = l[r0];
    }
  }
}

// ------------------------------ K3: pack -----------------------------------
// grid 256 = (b4 x 64 f-blocks of 64). Vpp[b][c][f'] = Vp[b][pi(f)][c]/L.
__global__ void __launch_bounds__(256) k_pack(const float* __restrict__ Vp,
                                              const float* __restrict__ Lpart,
                                              unsigned short* __restrict__ Vpp) {
  int b = blockIdx.x >> 6, f0 = (blockIdx.x & 63) * 64;
  __shared__ unsigned short Tt[32][72];            // [c][f-local], +8 pad
  int t = threadIdx.x;
  int floc = t & 63, cq = t >> 6;                  // 4 c-quads of 8 channels
  size_t li = (size_t)b * 4096 + f0 + floc;
  float L = 0.f;
#pragma unroll
  for (int p = 0; p < 16; ++p) L += Lpart[(size_t)p * 16384 + li];
  float rl = 1.0f / L;
  const float* vp = Vp + li * 32 + cq * 8;
  float4 v0 = *reinterpret_cast<const float4*>(vp);
  float4 v1 = *reinterpret_cast<const float4*>(vp + 4);
  int fl = (floc & ~15) | pi16(floc & 15);         // destination column
  Tt[cq * 8 + 0][fl] = f2bf(v0.x * rl);
  Tt[cq * 8 + 1][fl] = f2bf(v0.y * rl);
  Tt[cq * 8 + 2][fl] = f2bf(v0.z * rl);
  Tt[cq * 8 + 3][fl] = f2bf(v0.w * rl);
  Tt[cq * 8 + 4][fl] = f2bf(v1.x * rl);
  Tt[cq * 8 + 5][fl] = f2bf(v1.y * rl);
  Tt[cq * 8 + 6][fl] = f2bf(v1.z * rl);
  Tt[cq * 8 + 7][fl] = f2bf(v1.w * rl);
  __syncthreads();
  int row = t >> 3, seg = t & 7;                   // 32 rows x 8 uint4
  uint4 val = *reinterpret_cast<const uint4*>(&Tt[row][seg * 8]);
  *reinterpret_cast<uint4*>(Vpp + ((size_t)b * 32 + row) * 4096 + f0 + seg * 8) = val;
}

// ------------------------- K4: attention + project --------------------------
// 256 thr (4 waves) per 64-k pair, grid 1024, KB=2, f split 4-ways.
// x2-unrolled ping-pong: per half [2 produce-MFMA][3 VMEM][80 exp VALU]
// [4 PV-MFMA], schedule pinned with sched_group_barrier; (256,3) so the
// ~140-VGPR two-bank pipeline is not collapsed by RA.
__global__ void __launch_bounds__(256, 3) k_attn(const unsigned short* __restrict__ Qp,
                                                 const unsigned short* __restrict__ KpB,
                                                 const unsigned short* __restrict__ Vpp,
                                                 const unsigned short* __restrict__ Wop,
                                                 const float* __restrict__ x,
                                                 const float* __restrict__ gamma,
                                                 float* __restrict__ out) {
  int b = blockIdx.x >> 8, kp = blockIdx.x & 255;
  int wv = threadIdx.x >> 6, lane = threadIdx.x & 63;
  int half = lane >> 5, l31 = lane & 31;
  int kbase = kp * 64;
  const unsigned short* qb = Qp + ((size_t)b * 16384 + kbase + l31) * 16 + half * 8;
  bf8_t Bq0 = *reinterpret_cast<const bf8_t*>(qb);
  bf8_t Bq1 = *reinterpret_cast<const bf8_t*>(qb + 32 * 16);
  fx16 z;
#pragma unroll
  for (int i = 0; i < 16; ++i) z[i] = 0.f;
  fx16 acc0 = z, acc1 = z;
  const unsigned short* kpB = KpB + ((size_t)b * 4096 + l31) * 16 + half * 8;
  const unsigned short* vpB = Vpp + ((size_t)(b * 32 + l31)) * 4096 + half * 8;
  int c0 = wv * 32;                                // wave's first f-chunk
#define KLD(j) (*reinterpret_cast<const bf8_t*>(kpB + (size_t)((c0 + ((j) & 31)) * 32) * 16))
#define VLD(j, o) (*reinterpret_cast<const bf8_t*>(vpB + (c0 + ((j) & 31)) * 32 + (o)))
  bf8_t Ak0 = KLD(0);
  bf8_t VE0 = VLD(0, 0), VE1 = VLD(0, 16);
  fx16 sE0 = MFMA(Ak0, Bq0, z, 0, 0, 0);           // S chunk 0
  fx16 sE1 = MFMA(Ak0, Bq1, z, 0, 0, 0);
  bf8_t AkO = KLD(1);
  for (int it = 0; it < 16; ++it) {
    int e = 2 * it;
    // ---- half 1: produce S(e+1); prefetch V(e+1), K(e+2); consume S(e) ----
    fx16 sO0 = MFMA(AkO, Bq0, z, 0, 0, 0);
    fx16 sO1 = MFMA(AkO, Bq1, z, 0, 0, 0);
    bf8_t VO0 = VLD(e + 1, 0), VO1 = VLD(e + 1, 16);
    bf8_t AkE = KLD(e + 2);
    {
      uint4 u00, u01, u10, u11;
      u00.x = fe_pk(sE0[0], sE0[1]);   u00.y = fe_pk(sE0[2], sE0[3]);
      u00.z = fe_pk(sE0[4], sE0[5]);   u00.w = fe_pk(sE0[6], sE0[7]);
      u01.x = fe_pk(sE0[8], sE0[9]);   u01.y = fe_pk(sE0[10], sE0[11]);
      u01.z = fe_pk(sE0[12], sE0[13]); u01.w = fe_pk(sE0[14], sE0[15]);
      u10.x = fe_pk(sE1[0], sE1[1]);   u10.y = fe_pk(sE1[2], sE1[3]);
      u10.z = fe_pk(sE1[4], sE1[5]);   u10.w = fe_pk(sE1[6], sE1[7]);
      u11.x = fe_pk(sE1[8], sE1[9]);   u11.y = fe_pk(sE1[10], sE1[11]);
      u11.z = fe_pk(sE1[12], sE1[13]); u11.w = fe_pk(sE1[14], sE1[15]);
      acc0 = MFMA(VE0, __builtin_bit_cast(bf8_t, u00), acc0, 0, 0, 0);
      acc0 = MFMA(VE1, __builtin_bit_cast(bf8_t, u01), acc0, 0, 0, 0);
      acc1 = MFMA(VE0, __builtin_bit_cast(bf8_t, u10), acc1, 0, 0, 0);
      acc1 = MFMA(VE1, __builtin_bit_cast(bf8_t, u11), acc1, 0, 0, 0);
    }
    SGB(0x8, 2); SGB(0x20, 3); SGB(0x2, 80); SGB(0x8, 4);
    // ---- half 2: produce S(e+2); prefetch V(e+2), K(e+3); consume S(e+1) --
    sE0 = MFMA(AkE, Bq0, z, 0, 0, 0);
    sE1 = MFMA(AkE, Bq1, z, 0, 0, 0);
    VE0 = VLD(e + 2, 0); VE1 = VLD(e + 2, 16);
    AkO = KLD(e + 3);
    {
      uint4 u00, u01, u10, u11;
      u00.x = fe_pk(sO0[0], sO0[1]);   u00.y = fe_pk(sO0[2], sO0[3]);
      u00.z = fe_pk(sO0[4], sO0[5]);   u00.w = fe_pk(sO0[6], sO0[7]);
      u01.x = fe_pk(sO0[8], sO0[9]);   u01.y = fe_pk(sO0[10], sO0[11]);
      u01.z = fe_pk(sO0[12], sO0[13]); u01.w = fe_pk(sO0[14], sO0[15]);
      u10.x = fe_pk(sO1[0], sO1[1]);   u10.y = fe_pk(sO1[2], sO1[3]);
      u10.z = fe_pk(sO1[4], sO1[5]);   u10.w = fe_pk(sO1[6], sO1[7]);
      u11.x = fe_pk(sO1[8], sO1[9]);   u11.y = fe_pk(sO1[10], sO1[11]);
      u11.z = fe_pk(sO1[12], sO1[13]); u11.w = fe_pk(sO1[14], sO1[15]);
      acc0 = MFMA(VO0, __builtin_bit_cast(bf8_t, u00), acc0, 0, 0, 0);
      acc0 = MFMA(VO1, __builtin_bit_cast(bf8_t, u01), acc0, 0, 0, 0);
      acc1 = MFMA(VO0, __builtin_bit_cast(bf8_t, u10), acc1, 0, 0, 0);
      acc1 = MFMA(VO1, __builtin_bit_cast(bf8_t, u11), acc1, 0, 0, 0);
    }
    SGB(0x8, 2); SGB(0x20, 3); SGB(0x2, 80); SGB(0x8, 4);
  }
#undef KLD
#undef VLD
  __shared__ float sacc[4][2][4][64][4];           // 32 KB
#pragma unroll
  for (int j4 = 0; j4 < 4; ++j4) {
    *reinterpret_cast<float4*>(&sacc[wv][0][j4][lane][0]) =
        make_float4(acc0[4 * j4], acc0[4 * j4 + 1], acc0[4 * j4 + 2], acc0[4 * j4 + 3]);
    *reinterpret_cast<float4*>(&sacc[wv][1][j4][lane][0]) =
        make_float4(acc1[4 * j4], acc1[4 * j4 + 1], acc1[4 * j4 + 2], acc1[4 * j4 + 3]);
  }
  __syncthreads();
  if (wv >= 2) return;
  int kt = wv;
  int k = kbase + kt * 32 + l31;
  const float* xp = x + (size_t)b * 64 * 16384 + k;
  float xv0[16], xv1[16];                          // early residual prefetch
#pragma unroll
  for (int r0 = 0; r0 < 16; ++r0) {
    int row = (r0 & 3) + 8 * (r0 >> 2) + 4 * half;
    xv0[r0] = xp[(size_t)row * 16384];
    xv1[r0] = xp[(size_t)(row + 32) * 16384];
  }
  fx16 tot;
#pragma unroll
  for (int j4 = 0; j4 < 4; ++j4) {
    float4 a0 = *reinterpret_cast<const float4*>(&sacc[0][kt][j4][lane][0]);
    float4 a1 = *reinterpret_cast<const float4*>(&sacc[1][kt][j4][lane][0]);
    float4 a2 = *reinterpret_cast<const float4*>(&sacc[2][kt][j4][lane][0]);
    float4 a3 = *reinterpret_cast<const float4*>(&sacc[3][kt][j4][lane][0]);
    tot[4 * j4]     = (a0.x + a1.x) + (a2.x + a3.x);
    tot[4 * j4 + 1] = (a0.y + a1.y) + (a2.y + a3.y);
    tot[4 * j4 + 2] = (a0.z + a1.z) + (a2.z + a3.z);
    tot[4 * j4 + 3] = (a0.w + a1.w) + (a2.w + a3.w);
  }
  bf8_t Ob0, Ob1;
#pragma unroll
  for (int j = 0; j < 8; ++j) { Ob0[j] = (__bf16)tot[j]; Ob1[j] = (__bf16)tot[8 + j]; }
  const unsigned short* wb = Wop + l31 * 32 + half * 8;
  bf8_t Aw00 = *reinterpret_cast<const bf8_t*>(wb);
  bf8_t Aw01 = *reinterpret_cast<const bf8_t*>(wb + 16);
  bf8_t Aw10 = *reinterpret_cast<const bf8_t*>(wb + 1024);
  bf8_t Aw11 = *reinterpret_cast<const bf8_t*>(wb + 1024 + 16);
  fx16 y0 = MFMA(Aw00, Ob0, z, 0, 0, 0);
  y0 = MFMA(Aw01, Ob1, y0, 0, 0, 0);
  fx16 y1 = MFMA(Aw10, Ob0, z, 0, 0, 0);
  y1 = MFMA(Aw11, Ob1, y1, 0, 0, 0);
  float g = gamma[0];
  float* op = out + (size_t)b * 64 * 16384 + k;
#pragma unroll
  for (int r0 = 0; r0 < 16; ++r0) {
    int row = (r0 & 3) + 8 * (r0 >> 2) + 4 * half;
    op[(size_t)row * 16384]        = fmaf(g, y0[r0], xv0[r0]);
    op[(size_t)(row + 32) * 16384] = fmaf(g, y1[r0], xv1[r0]);
  }
}

// ---------------------------------------------------------------------------
extern "C" void kernel_launch(void* const* d_in, const int* in_sizes, int n_in,
                              void* d_out, int out_size, void* d_ws, size_t ws_size,
                              hipStream_t stream) {
  const float* x     = (const float*)d_in[0];
  const float* Wq    = (const float*)d_in[1];
  const float* Wk    = (const float*)d_in[2];
  const float* Wv    = (const float*)d_in[3];
  const float* Wo    = (const float*)d_in[4];
  const float* gamma = (const float*)d_in[5];
  float* out = (float*)d_out;
  char* ws = (char*)d_ws;
  // workspace layout (bytes)
  unsigned short* Qp    = (unsigned short*)(ws + 0);        // 2 MB
  unsigned short* KpB   = (unsigned short*)(ws + 2097152);  // 512 KB
  float*          Vp    = (float*)(ws + 2621440);           // 2 MB
  unsigned short* Vpp   = (unsigned short*)(ws + 4718592);  // 1 MB
  float*          Lpart = (float*)(ws + 5767168);           // 1 MB (16 planes)
  unsigned short* Wop   = (unsigned short*)(ws + 6815744);  // 4 KB

  k_qkv <<<dim3(513),  dim3(256), 0, stream>>>(x, Wq, Wk, Wv, Wo, Qp, KpB, Vp, Wop);
  k_lsum<<<dim3(4096), dim3(128), 0, stream>>>(Qp, KpB, Lpart);
  k_pack<<<dim3(256),  dim3(256), 0, stream>>>(Vp, Lpart, Vpp);
  k_attn<<<dim3(1024), dim3(256), 0, stream>>>(Qp, KpB, Vpp, Wop, x, gamma, out);
}